// Round 2
// baseline (130.310 us; speedup 1.0000x reference)
//
#include <hip/hip_runtime.h>
#include <hip/hip_bf16.h>

// Problem constants
#define N_NODES 8
#define N_EDGES 64
#define CO 64
#define OH 128
#define OW 128
#define FEAT 1024
#define BN_EPS 1e-5f

// Workspace layout (bytes):
//   partial @ 0        : 16 rt x 36 pairs x 64 c fp32 = 147,456 (pad 151,552)
//   (xpad region now unused — conv stages directly from x)
//   wb2     @ 3471616  : 24*128*8 bf16 = 49,152
//   A2      @ 3520768  : 16,777,216
//   B2      @ 20297984 : 16,777,216
//   fc_wT   @ 37075200 : 64*1024 f32 = 262,144   (built by pool_kernel)
#define OFF_PARTIAL 0
#define OFF_WB      3471616
#define OFF_A       3520768
#define OFF_B       20297984
#define OFF_FCWT    37075200

#define RS_W 136        // conv raw row stride in u32 words

typedef short bf16x8 __attribute__((ext_vector_type(8)));
typedef float f32x4  __attribute__((ext_vector_type(4)));

__device__ __forceinline__ unsigned short f2bf(float f) {   // RNE f32->bf16
    unsigned u = __float_as_uint(f);
    u += 0x7fffu + ((u >> 16) & 1u);
    return (unsigned short)(u >> 16);
}
__device__ __forceinline__ float blo(unsigned u) { return __uint_as_float(u << 16); }
__device__ __forceinline__ float bhi(unsigned u) { return __uint_as_float(u & 0xffff0000u); }

// ---------------------------------------------------------------------------
// K0: micro-prep — wb2 weight repack only (96 blocks). Image pad/convert is
// inlined into conv staging; fc_wT build folded into pool_kernel.
__global__ __launch_bounds__(256) void prep_kernel(
        const float* __restrict__ w,
        const float* __restrict__ gamma, const float* __restrict__ var,
        unsigned short* __restrict__ wb2) {
    int idx = blockIdx.x * 256 + threadIdx.x;
    if (idx < 2 * 64 * 192) {
        int tp = idx % 192;
        int c  = (idx / 192) & 63;
        int h  = idx / (192 * 64);
        int rr = tp >> 3, kx = tp & 7;
        float val = 0.f;
        if (rr < 21 && kx < 7) {
            int ci = rr / 7, ky = rr % 7;
            float sc = gamma[c] * rsqrtf(var[c] + BN_EPS);
            val = w[((c * 6 + h * 3 + ci) * 7 + ky) * 7 + kx] * sc;
        }
        wb2[(rr * 128 + h * 64 + c) * 8 + kx] = f2bf(val);
    }
}

// ---------------------------------------------------------------------------
// K1: MFMA conv. Staging now reads x (fp32) directly, converting/padding
// inline — eliminates the xpad workspace round-trip (prep 10 MB + conv read).
// Wave = (hg = A/B half, wg = px half): 64px x 64chp register tile,
// acc[4][4] = 64 VGPR; 16 MFMA per afrag/wfrag fetch group (0.5 KB/MFMA).
__global__ __launch_bounds__(256, 3) void conv_kernel(
        const float* __restrict__ x, const unsigned short* __restrict__ wb2,
        const float* __restrict__ gamma, const float* __restrict__ beta,
        const float* __restrict__ mean,  const float* __restrict__ var,
        unsigned short* __restrict__ A2, unsigned short* __restrict__ B2) {
    int bx  = blockIdx.x;
    int r16 = bx & 7;                  // XCD-pinned row-group (matches pool)
    int idx = bx >> 3;
    int n   = idx >> 4;
    int oy  = (r16 << 4) + (idx & 15);
    int t   = threadIdx.x;

    // one 32 KB buffer: rawu [24][136] u32 (13 KB), reused as T [128][128] bf16
    __shared__ __align__(16) char smem[32768];
    unsigned* rawu = (unsigned*)smem;

    // stage: 24 rows x 34 granules (granule = 4 u32 = 8 bf16 cols, col0=8g-3)
    // rows 21-23 and granule 33 zeroed. Inline fp32->bf16 + border pad.
    const float* xn = x + (size_t)n * (3 * 65536);
    for (int k = t; k < 816; k += 256) {
        int g  = k % 34;
        int rr = k / 34;
        uint4 v = make_uint4(0u, 0u, 0u, 0u);
        if (rr < 21 && g < 33) {
            int ci = (rr * 147) >> 10;  // rr/7 for rr<24
            int ky = rr - ci * 7;
            int iy = 2 * oy + ky - 3;
            if ((unsigned)iy < 256u) {
                const float* row = xn + ci * 65536 + iy * 256;
                int c0 = 8 * g - 3;
                float f[8];
#pragma unroll
                for (int j = 0; j < 8; ++j) {
                    int c  = c0 + j;
                    int cc = min(max(c, 0), 255);
                    float fv = row[cc];
                    f[j] = (c == cc) ? fv : 0.f;
                }
                v.x = (unsigned)f2bf(f[0]) | ((unsigned)f2bf(f[1]) << 16);
                v.y = (unsigned)f2bf(f[2]) | ((unsigned)f2bf(f[3]) << 16);
                v.z = (unsigned)f2bf(f[4]) | ((unsigned)f2bf(f[5]) << 16);
                v.w = (unsigned)f2bf(f[6]) | ((unsigned)f2bf(f[7]) << 16);
            }
        }
        *(uint4*)&rawu[rr * RS_W + 4 * g] = v;
    }
    __syncthreads();

    int wv = t >> 6, lane = t & 63;
    int hg = wv >> 1;                   // A/B half (chp 0-63 vs 64-127)
    int wg = wv & 1;                    // px half (64 px)
    int quad = lane >> 4, m = lane & 15;

    f32x4 acc[4][4];
#pragma unroll
    for (int ct = 0; ct < 4; ++ct)
#pragma unroll
        for (int nt = 0; nt < 4; ++nt)
            acc[ct][nt] = (f32x4){0.f, 0.f, 0.f, 0.f};

    const bf16x8* wbv = (const bf16x8*)wb2;

#pragma unroll 2
    for (int s = 0; s < 6; ++s) {
        int rq = 4 * s + quad;
        bf16x8 afrag[4];                // image: A[m=px][k]
#pragma unroll
        for (int nt = 0; nt < 4; ++nt) {
            int ox = 64 * wg + 16 * nt + m;
            int base = rq * RS_W + ox;
            union { unsigned u[4]; bf16x8 v; } bb;
            bb.u[0] = rawu[base];     bb.u[1] = rawu[base + 1];
            bb.u[2] = rawu[base + 2]; bb.u[3] = rawu[base + 3];
            afrag[nt] = bb.v;
        }
#pragma unroll
        for (int ct = 0; ct < 4; ++ct) {
            bf16x8 wfrag = wbv[rq * 128 + hg * 64 + 16 * ct + m];  // L1-hot
#pragma unroll
            for (int nt = 0; nt < 4; ++nt)
                acc[ct][nt] = __builtin_amdgcn_mfma_f32_16x16x32_bf16(
                                  afrag[nt], wfrag, acc[ct][nt], 0, 0, 0);
        }
    }

    float sh[4] = {0.f, 0.f, 0.f, 0.f};
    if (hg) {                           // BN shift folded into B-half only
#pragma unroll
        for (int ct = 0; ct < 4; ++ct) {
            int c = 16 * ct + m;
            float sc = gamma[c] * rsqrtf(var[c] + BN_EPS);
            sh[ct] = beta[c] - mean[c] * sc;
        }
    }

    __syncthreads();                    // smem reuse: T transpose buffer
    unsigned short* T = (unsigned short*)smem;   // [128 chp][128 px], swizzled

#pragma unroll
    for (int ct = 0; ct < 4; ++ct) {
        int chp = hg * 64 + 16 * ct + m;
        int sw  = (chp & 7) << 2;       // XOR swizzle key (granule = 4 shorts)
#pragma unroll
        for (int nt = 0; nt < 4; ++nt) {
            int px0 = 64 * wg + 16 * nt + 4 * quad;
            float v0 = acc[ct][nt][0] + sh[ct];
            float v1 = acc[ct][nt][1] + sh[ct];
            float v2 = acc[ct][nt][2] + sh[ct];
            float v3 = acc[ct][nt][3] + sh[ct];
            uint2 pk;
            pk.x = (unsigned)f2bf(v0) | ((unsigned)f2bf(v1) << 16);
            pk.y = (unsigned)f2bf(v2) | ((unsigned)f2bf(v3) << 16);
            int gs = ((px0 >> 2) ^ sw);
            *(uint2*)&T[chp * 128 + gs * 4] = pk;
        }
    }
    __syncthreads();

    // coalesced store: 4 passes of (32 ch-rows x 8 16-px slots), 2x uint4 each
#pragma unroll
    for (int rr = 0; rr < 4; ++rr) {
        int row = rr * 32 + (t >> 3), slot = t & 7;
        int hh = row >> 6, ch = row & 63;
        int swr = (row & 7) << 2;
        unsigned short* dst = (hh ? B2 : A2)
                            + ((size_t)(n * CO + ch) << 14) + (oy << 7) + slot * 16;
#pragma unroll
        for (int i = 0; i < 2; ++i) {
            int g  = slot * 4 + i * 2;  // granule of px slot*16 + i*8
            int gs = g ^ swr;
            *(uint4*)(dst + i * 8) = *(uint4*)&T[row * 128 + gs * 4];
        }
    }
}

// ---------------------------------------------------------------------------
// K2: pool over 36 distinct pairs. RESTRUCTURED: 576 thr (9 waves x 4 slots
// x 16 tc) = 36 slots in ONE iteration (was 3 iters x 48 slots, 25% idle).
// Also builds fc_wT (transposed fc_w) for head: 64 lanes/block, exact cover.
__global__ __launch_bounds__(576) void pool_kernel(
        const unsigned short* __restrict__ A2,
        const unsigned short* __restrict__ B2,
        const float* __restrict__ fc_w,
        float* __restrict__ partial, float* __restrict__ fc_wT) {
    int pb  = blockIdx.x;
    int xcd = pb & 7;
    int q   = pb >> 3;
    int c   = q >> 1;
    int rt  = xcd * 2 + (q & 1);
    int t   = threadIdx.x;

    // fc_wT[c'][f] = fc_w[f][c']: 1024 blocks x 64 lanes = 65536 exact
    if (t < 64) {
        int idx = pb * 64 + t;
        int cc = idx >> 10, f = idx & 1023;
        fc_wT[idx] = fc_w[f * CO + cc];
    }

    __shared__ unsigned short S[2 * 8 * 9 * 128];   // plane 1152, row 128

    for (int k = t; k < 2304; k += 576) {
        int slot = k & 15;
        int r    = (k >> 4) % 9;
        int tn   = (k >> 4) / 9;
        int grow = 8 * rt - 1 + r;
        uint4 v = make_uint4(0u, 0u, 0u, 0u);
        if (grow >= 0) {
            const unsigned short* src = (tn >= 8) ? B2 : A2;
            int node = tn & 7;
            v = *(const uint4*)(src + ((size_t)(node * CO + c) << 14)
                                    + (grow << 7) + slot * 8);
        }
        *(uint4*)&S[tn * 1152 + (r << 7) + slot * 8] = v;
    }
    __syncthreads();

    int wv = t >> 6, lane = t & 63;
    int esub = lane >> 4, tc = lane & 15;

    int sidx = 4 * wv + esub;                        // pair slot 0..35, all valid
    int pi = 0, rem = sidx;                          // unrank (pi<=pj)
    while (rem >= 8 - pi) { rem -= 8 - pi; ++pi; }
    int pj = pi + rem;
    const unsigned short* pa  = &S[pi * 1152];
    const unsigned short* pb2 = &S[(8 + pj) * 1152];

    float mx[4][4];
#pragma unroll
    for (int p = 0; p < 4; ++p)
#pragma unroll
        for (int qq = 0; qq < 4; ++qq) mx[p][qq] = 0.f;

#pragma unroll
    for (int r = 0; r < 9; ++r) {
        uint4 ga = *(const uint4*)(pa + (r << 7) + tc * 8);
        uint4 gb = *(const uint4*)(pb2 + (r << 7) + tc * 8);
        float ha = 0.f, hb = 0.f;
        if (tc > 0) {
            ha = bhi(*(const unsigned*)(pa + (r << 7) + tc * 8 - 2));
            hb = bhi(*(const unsigned*)(pb2 + (r << 7) + tc * 8 - 2));
        }
        float z0 = ha + hb;
        float z1 = blo(ga.x) + blo(gb.x), z2 = bhi(ga.x) + bhi(gb.x);
        float z3 = blo(ga.y) + blo(gb.y), z4 = bhi(ga.y) + bhi(gb.y);
        float z5 = blo(ga.z) + blo(gb.z), z6 = bhi(ga.z) + bhi(gb.z);
        float z7 = blo(ga.w) + blo(gb.w), z8 = bhi(ga.w) + bhi(gb.w);
        float h0 = fmaxf(fmaxf(z0, z1), z2);
        float h1 = fmaxf(fmaxf(z2, z3), z4);
        float h2 = fmaxf(fmaxf(z4, z5), z6);
        float h3 = fmaxf(fmaxf(z6, z7), z8);
        if (r & 1) {
            int p = (r - 1) >> 1;
            mx[p][0] = fmaxf(mx[p][0], h0); mx[p][1] = fmaxf(mx[p][1], h1);
            mx[p][2] = fmaxf(mx[p][2], h2); mx[p][3] = fmaxf(mx[p][3], h3);
        } else {
            if (r >= 2) {
                int p = (r >> 1) - 1;
                mx[p][0] = fmaxf(mx[p][0], h0); mx[p][1] = fmaxf(mx[p][1], h1);
                mx[p][2] = fmaxf(mx[p][2], h2); mx[p][3] = fmaxf(mx[p][3], h3);
            }
            if (r <= 6) {
                int p = r >> 1;
                mx[p][0] = fmaxf(mx[p][0], h0); mx[p][1] = fmaxf(mx[p][1], h1);
                mx[p][2] = fmaxf(mx[p][2], h2); mx[p][3] = fmaxf(mx[p][3], h3);
            }
        }
    }

    float sum = 0.f;
#pragma unroll
    for (int p = 0; p < 4; ++p)
#pragma unroll
        for (int qq = 0; qq < 4; ++qq) sum += fmaxf(mx[p][qq], 0.f);

    sum += __shfl_down(sum, 8, 64);
    sum += __shfl_down(sum, 4, 64);
    sum += __shfl_down(sum, 2, 64);
    sum += __shfl_down(sum, 1, 64);
    if (tc == 0)
        partial[(rt * 36 + sidx) * 64 + c] = sum;
}

// ---------------------------------------------------------------------------
// K3: head — 64 blocks x 1024 thr, thread t = feature f; fc_wT coalesced.
__global__ __launch_bounds__(1024) void head_kernel(
        const int* __restrict__ ei, const float* __restrict__ partial,
        const float* __restrict__ fc_wT,  const float* __restrict__ fc_b,
        const float* __restrict__ xyz_w,  const float* __restrict__ xyz_b,
        const float* __restrict__ wpqr_w, const float* __restrict__ wpqr_b,
        float* __restrict__ out) {
    int e = blockIdx.x;
    int t = threadIdx.x;                 // = feature index f
    int a0 = ei[e], a1 = ei[N_EDGES + e];
    int pi = min(a0, a1), pj = max(a0, a1);
    int rank = pi * 8 - ((pi * (pi + 1)) >> 1) + pj;
    __shared__ float pl[CO];
    if (t < CO) {
        float s = 0.f;
#pragma unroll
        for (int rt = 0; rt < 16; ++rt)
            s += partial[(rt * 36 + rank) * 64 + t];
        pl[t] = s * (1.f / 4096.f);
    }
    __syncthreads();

    float d = fc_b[t];
#pragma unroll
    for (int c = 0; c < CO; ++c)
        d = fmaf(pl[c], fc_wT[c * FEAT + t], d);
    d = fmaxf(d, 0.f);

    float s[6];
#pragma unroll
    for (int r = 0; r < 3; ++r) {
        s[r]     = d * xyz_w[r * FEAT + t];
        s[3 + r] = d * wpqr_w[r * FEAT + t];
    }
#pragma unroll
    for (int r = 0; r < 6; ++r)
#pragma unroll
        for (int off = 32; off > 0; off >>= 1)
            s[r] += __shfl_down(s[r], off, 64);

    __shared__ float red[16][6];
    if ((t & 63) == 0) {
#pragma unroll
        for (int r = 0; r < 6; ++r) red[t >> 6][r] = s[r];
    }
    __syncthreads();
    if (t < 6) {
        float v = 0.f;
#pragma unroll
        for (int w = 0; w < 16; ++w) v += red[w][t];
        v += (t < 3) ? xyz_b[t] : wpqr_b[t - 3];
        out[48 + e * 6 + t] = v;
        if (e < 8) out[e * 6 + t] = v;
    }
}

// ---------------------------------------------------------------------------
extern "C" void kernel_launch(void* const* d_in, const int* in_sizes, int n_in,
                              void* d_out, int out_size, void* d_ws, size_t ws_size,
                              hipStream_t stream) {
    const float* x        = (const float*)d_in[0];
    const int*   ei       = (const int*)d_in[1];
    const float* conv1_w  = (const float*)d_in[2];
    const float* bn_gamma = (const float*)d_in[3];
    const float* bn_beta  = (const float*)d_in[4];
    const float* bn_mean  = (const float*)d_in[5];
    const float* bn_var   = (const float*)d_in[6];
    const float* fc_w     = (const float*)d_in[7];
    const float* fc_b     = (const float*)d_in[8];
    const float* xyz_w    = (const float*)d_in[9];
    const float* xyz_b    = (const float*)d_in[10];
    const float* wpqr_w   = (const float*)d_in[11];
    const float* wpqr_b   = (const float*)d_in[12];
    float* out = (float*)d_out;

    char* ws = (char*)d_ws;
    float*          partial = (float*)(ws + OFF_PARTIAL);
    unsigned short* wb2     = (unsigned short*)(ws + OFF_WB);
    unsigned short* A2      = (unsigned short*)(ws + OFF_A);
    unsigned short* B2      = (unsigned short*)(ws + OFF_B);
    float*          fc_wT   = (float*)(ws + OFF_FCWT);

    prep_kernel<<<96, 256, 0, stream>>>(conv1_w, bn_gamma, bn_var, wb2);
    conv_kernel<<<1024, 256, 0, stream>>>(x, wb2, bn_gamma, bn_beta,
                                          bn_mean, bn_var, A2, B2);
    pool_kernel<<<1024, 576, 0, stream>>>(A2, B2, fc_w, partial, fc_wT);
    head_kernel<<<64, 1024, 0, stream>>>(ei, partial, fc_wT, fc_b,
                                         xyz_w, xyz_b, wpqr_w, wpqr_b, out);
}

// Round 3
// 121.310 us; speedup vs baseline: 1.0742x; 1.0742x over previous
//
#include <hip/hip_runtime.h>
#include <hip/hip_bf16.h>

// Problem constants
#define N_NODES 8
#define N_EDGES 64
#define CO 64
#define OH 128
#define OW 128
#define FEAT 1024
#define BN_EPS 1e-5f

// Workspace layout (bytes):
//   partial @ 0        : 16 rt x 36 pairs x 64 c fp32 = 147,456 (pad 151,552)
//   xpad    @ 151552   : 8*3*262*264 bf16 = 3,320,064
//   wb2     @ 3471616  : 24*128*8 bf16 = 49,152
//   A2      @ 3520768  : 16,777,216
//   B2      @ 20297984 : 16,777,216
//   fc_wT   @ 37075200 : 64*1024 f32 = 262,144
#define OFF_PARTIAL 0
#define OFF_XPAD    151552
#define OFF_WB      3471616
#define OFF_A       3520768
#define OFF_B       20297984
#define OFF_FCWT    37075200

#define RS_W 136        // conv raw row stride in u32 words
#define XROW 132        // xpad row stride in u32 words

typedef short bf16x8 __attribute__((ext_vector_type(8)));
typedef float f32x4  __attribute__((ext_vector_type(4)));

__device__ __forceinline__ unsigned short f2bf(float f) {   // RNE f32->bf16
    unsigned u = __float_as_uint(f);
    u += 0x7fffu + ((u >> 16) & 1u);
    return (unsigned short)(u >> 16);
}
__device__ __forceinline__ float blo(unsigned u) { return __uint_as_float(u << 16); }
__device__ __forceinline__ float bhi(unsigned u) { return __uint_as_float(u & 0xffff0000u); }

// ---------------------------------------------------------------------------
// K0: prep — pad+convert image to bf16 (xpad) + weight repack + fc_w transpose.
// R2 lesson: keep this pass — vectorized L2-hot xpad reload in conv beats
// scattered inline fp32 conversion by ~11 us.
__global__ __launch_bounds__(256) void prep_kernel(
        const float* __restrict__ x, const float* __restrict__ w,
        const float* __restrict__ gamma, const float* __restrict__ var,
        const float* __restrict__ fc_w,
        unsigned* __restrict__ xpad, unsigned short* __restrict__ wb2,
        float* __restrict__ fc_wT) {
    int idx = blockIdx.x * 256 + threadIdx.x;
    if (idx < 8 * 3 * 262 * XROW) {
        int u   = idx % XROW;
        int r   = idx / XROW;
        int iyp = r % 262;
        int nc  = r / 262;
        int iy  = iyp - 3;
        unsigned val = 0u;
        if ((unsigned)iy < 256u) {
            int c0 = 2 * u - 3;
            const float* row = x + (size_t)nc * 65536 + iy * 256;
            float f0 = ((unsigned)c0 < 256u) ? row[c0] : 0.f;
            float f1 = ((unsigned)(c0 + 1) < 256u) ? row[c0 + 1] : 0.f;
            val = (unsigned)f2bf(f0) | ((unsigned)f2bf(f1) << 16);
        }
        xpad[idx] = val;
    }
    if (idx < 2 * 64 * 192) {
        int tp = idx % 192;
        int c  = (idx / 192) & 63;
        int h  = idx / (192 * 64);
        int rr = tp >> 3, kx = tp & 7;
        float val = 0.f;
        if (rr < 21 && kx < 7) {
            int ci = rr / 7, ky = rr % 7;
            float sc = gamma[c] * rsqrtf(var[c] + BN_EPS);
            val = w[((c * 6 + h * 3 + ci) * 7 + ky) * 7 + kx] * sc;
        }
        wb2[(rr * 128 + h * 64 + c) * 8 + kx] = f2bf(val);
    }
    if (idx < CO * FEAT) {                 // fc_wT[c][f] = fc_w[f][c]
        int c = idx >> 10, f = idx & 1023;
        fc_wT[idx] = fc_w[f * CO + c];
    }
}

// ---------------------------------------------------------------------------
// K1: MFMA conv. Wave = (hg = A/B half, wg = px half): 64px x 64chp register
// tile, acc[4][4] = 64 VGPR; 16 MFMA per afrag/wfrag fetch group.
// launch_bounds(256,4): cap VGPR at 128 (live set ~110-125 fits) -> 4 blocks/CU
// -> the 1024-block grid runs in ONE residency round (no 256-block tail at
// 1/4 occupancy, which (256,3) allowed if allocator exceeded 128 VGPR).
__global__ __launch_bounds__(256, 4) void conv_kernel(
        const unsigned* __restrict__ xpad, const unsigned short* __restrict__ wb2,
        const float* __restrict__ gamma, const float* __restrict__ beta,
        const float* __restrict__ mean,  const float* __restrict__ var,
        unsigned short* __restrict__ A2, unsigned short* __restrict__ B2) {
    int bx  = blockIdx.x;
    int r16 = bx & 7;                  // XCD-pinned row-group (matches pool)
    int idx = bx >> 3;
    int n   = idx >> 4;
    int oy  = (r16 << 4) + (idx & 15);
    int t   = threadIdx.x;

    // one 32 KB buffer: rawu [24][136] u32 (13 KB), reused as T [128][128] bf16
    __shared__ __align__(16) char smem[32768];
    unsigned* rawu = (unsigned*)smem;

    // stage: 24 rows x 34 uint4 granules (rows 21-23, granule 33 zeroed)
    const unsigned* src = xpad + (size_t)n * (3 * 262 * XROW);
    for (int k = t; k < 816; k += 256) {
        int g  = k % 34;
        int rr = k / 34;
        uint4 v = make_uint4(0u, 0u, 0u, 0u);
        if (rr < 21 && g < 33) {
            int ci = (rr * 147) >> 10;  // rr/7 for rr<24
            int ky = rr - ci * 7;
            v = *(const uint4*)(src + (ci * 262 + 2 * oy + ky) * XROW + 4 * g);
        }
        *(uint4*)&rawu[rr * RS_W + 4 * g] = v;
    }
    __syncthreads();

    int wv = t >> 6, lane = t & 63;
    int hg = wv >> 1;                   // A/B half (chp 0-63 vs 64-127)
    int wg = wv & 1;                    // px half (64 px)
    int quad = lane >> 4, m = lane & 15;

    f32x4 acc[4][4];
#pragma unroll
    for (int ct = 0; ct < 4; ++ct)
#pragma unroll
        for (int nt = 0; nt < 4; ++nt)
            acc[ct][nt] = (f32x4){0.f, 0.f, 0.f, 0.f};

    const bf16x8* wbv = (const bf16x8*)wb2;

#pragma unroll 2
    for (int s = 0; s < 6; ++s) {
        int rq = 4 * s + quad;
        bf16x8 afrag[4];                // image: A[m=px][k]
#pragma unroll
        for (int nt = 0; nt < 4; ++nt) {
            int ox = 64 * wg + 16 * nt + m;
            int base = rq * RS_W + ox;
            union { unsigned u[4]; bf16x8 v; } bb;
            bb.u[0] = rawu[base];     bb.u[1] = rawu[base + 1];
            bb.u[2] = rawu[base + 2]; bb.u[3] = rawu[base + 3];
            afrag[nt] = bb.v;
        }
#pragma unroll
        for (int ct = 0; ct < 4; ++ct) {
            bf16x8 wfrag = wbv[rq * 128 + hg * 64 + 16 * ct + m];  // L1-hot
#pragma unroll
            for (int nt = 0; nt < 4; ++nt)
                acc[ct][nt] = __builtin_amdgcn_mfma_f32_16x16x32_bf16(
                                  afrag[nt], wfrag, acc[ct][nt], 0, 0, 0);
        }
    }

    float sh[4] = {0.f, 0.f, 0.f, 0.f};
    if (hg) {                           // BN shift folded into B-half only
#pragma unroll
        for (int ct = 0; ct < 4; ++ct) {
            int c = 16 * ct + m;
            float sc = gamma[c] * rsqrtf(var[c] + BN_EPS);
            sh[ct] = beta[c] - mean[c] * sc;
        }
    }

    __syncthreads();                    // smem reuse: T transpose buffer
    unsigned short* T = (unsigned short*)smem;   // [128 chp][128 px], swizzled

#pragma unroll
    for (int ct = 0; ct < 4; ++ct) {
        int chp = hg * 64 + 16 * ct + m;
        int sw  = (chp & 7) << 2;       // XOR swizzle key (granule = 4 shorts)
#pragma unroll
        for (int nt = 0; nt < 4; ++nt) {
            int px0 = 64 * wg + 16 * nt + 4 * quad;
            float v0 = acc[ct][nt][0] + sh[ct];
            float v1 = acc[ct][nt][1] + sh[ct];
            float v2 = acc[ct][nt][2] + sh[ct];
            float v3 = acc[ct][nt][3] + sh[ct];
            uint2 pk;
            pk.x = (unsigned)f2bf(v0) | ((unsigned)f2bf(v1) << 16);
            pk.y = (unsigned)f2bf(v2) | ((unsigned)f2bf(v3) << 16);
            int gs = ((px0 >> 2) ^ sw);
            *(uint2*)&T[chp * 128 + gs * 4] = pk;
        }
    }
    __syncthreads();

    // coalesced store: 4 passes of (32 ch-rows x 8 16-px slots), 2x uint4 each
#pragma unroll
    for (int rr = 0; rr < 4; ++rr) {
        int row = rr * 32 + (t >> 3), slot = t & 7;
        int hh = row >> 6, ch = row & 63;
        int swr = (row & 7) << 2;
        unsigned short* dst = (hh ? B2 : A2)
                            + ((size_t)(n * CO + ch) << 14) + (oy << 7) + slot * 16;
#pragma unroll
        for (int i = 0; i < 2; ++i) {
            int g  = slot * 4 + i * 2;  // granule of px slot*16 + i*8
            int gs = g ^ swr;
            *(uint4*)(dst + i * 8) = *(uint4*)&T[row * 128 + gs * 4];
        }
    }
}

// ---------------------------------------------------------------------------
// K2: pool over 36 distinct pairs -> non-atomic partial[rt][pair][c].
// 320 thr (5 waves x 4 slots) x 2 iters = 40 slot-computations, 36 valid
// (10% waste vs 25% at 256x3; serial depth -33%). LDS 36.9 KB -> 4 blocks/CU
// = grid/CU exactly; 20 waves/CU; VGPR cap 512/5=102 >= ~70 live.
__global__ __launch_bounds__(320, 5) void pool_kernel(
        const unsigned short* __restrict__ A2,
        const unsigned short* __restrict__ B2,
        float* __restrict__ partial) {
    int pb  = blockIdx.x;
    int xcd = pb & 7;
    int q   = pb >> 3;
    int c   = q >> 1;
    int rt  = xcd * 2 + (q & 1);
    int t   = threadIdx.x;

    __shared__ unsigned short S[2 * 8 * 9 * 128];   // plane 1152, row 128

    for (int k = t; k < 2304; k += 320) {
        int slot = k & 15;
        int r    = (k >> 4) % 9;
        int tn   = (k >> 4) / 9;
        int grow = 8 * rt - 1 + r;
        uint4 v = make_uint4(0u, 0u, 0u, 0u);
        if (grow >= 0) {
            const unsigned short* src = (tn >= 8) ? B2 : A2;
            int node = tn & 7;
            v = *(const uint4*)(src + ((size_t)(node * CO + c) << 14)
                                    + (grow << 7) + slot * 8);
        }
        *(uint4*)&S[tn * 1152 + (r << 7) + slot * 8] = v;
    }
    __syncthreads();

    int wv = t >> 6, lane = t & 63;
    int esub = lane >> 4, tc = lane & 15;

    for (int i = 0; i < 2; ++i) {
        int sidx = 20 * i + 4 * wv + esub;          // pair slot 0..39
        bool valid = sidx < 36;
        int ss = valid ? sidx : 0;
        int pi = 0, rem = ss;                        // unrank (pi<=pj)
        while (rem >= 8 - pi) { rem -= 8 - pi; ++pi; }
        int pj = pi + rem;
        const unsigned short* pa  = &S[pi * 1152];
        const unsigned short* pb2 = &S[(8 + pj) * 1152];

        float mx[4][4];
#pragma unroll
        for (int p = 0; p < 4; ++p)
#pragma unroll
            for (int qq = 0; qq < 4; ++qq) mx[p][qq] = 0.f;

#pragma unroll
        for (int r = 0; r < 9; ++r) {
            uint4 ga = *(const uint4*)(pa + (r << 7) + tc * 8);
            uint4 gb = *(const uint4*)(pb2 + (r << 7) + tc * 8);
            float ha = 0.f, hb = 0.f;
            if (tc > 0) {
                ha = bhi(*(const unsigned*)(pa + (r << 7) + tc * 8 - 2));
                hb = bhi(*(const unsigned*)(pb2 + (r << 7) + tc * 8 - 2));
            }
            float z0 = ha + hb;
            float z1 = blo(ga.x) + blo(gb.x), z2 = bhi(ga.x) + bhi(gb.x);
            float z3 = blo(ga.y) + blo(gb.y), z4 = bhi(ga.y) + bhi(gb.y);
            float z5 = blo(ga.z) + blo(gb.z), z6 = bhi(ga.z) + bhi(gb.z);
            float z7 = blo(ga.w) + blo(gb.w), z8 = bhi(ga.w) + bhi(gb.w);
            float h0 = fmaxf(fmaxf(z0, z1), z2);
            float h1 = fmaxf(fmaxf(z2, z3), z4);
            float h2 = fmaxf(fmaxf(z4, z5), z6);
            float h3 = fmaxf(fmaxf(z6, z7), z8);
            if (r & 1) {
                int p = (r - 1) >> 1;
                mx[p][0] = fmaxf(mx[p][0], h0); mx[p][1] = fmaxf(mx[p][1], h1);
                mx[p][2] = fmaxf(mx[p][2], h2); mx[p][3] = fmaxf(mx[p][3], h3);
            } else {
                if (r >= 2) {
                    int p = (r >> 1) - 1;
                    mx[p][0] = fmaxf(mx[p][0], h0); mx[p][1] = fmaxf(mx[p][1], h1);
                    mx[p][2] = fmaxf(mx[p][2], h2); mx[p][3] = fmaxf(mx[p][3], h3);
                }
                if (r <= 6) {
                    int p = r >> 1;
                    mx[p][0] = fmaxf(mx[p][0], h0); mx[p][1] = fmaxf(mx[p][1], h1);
                    mx[p][2] = fmaxf(mx[p][2], h2); mx[p][3] = fmaxf(mx[p][3], h3);
                }
            }
        }

        float sum = 0.f;
#pragma unroll
        for (int p = 0; p < 4; ++p)
#pragma unroll
            for (int qq = 0; qq < 4; ++qq) sum += fmaxf(mx[p][qq], 0.f);

        sum += __shfl_down(sum, 8, 64);
        sum += __shfl_down(sum, 4, 64);
        sum += __shfl_down(sum, 2, 64);
        sum += __shfl_down(sum, 1, 64);
        if (tc == 0 && valid)
            partial[(rt * 36 + sidx) * 64 + c] = sum;
    }
}

// ---------------------------------------------------------------------------
// K3: head — 64 blocks x 1024 thr, thread t = feature f; fc_wT coalesced.
__global__ __launch_bounds__(1024) void head_kernel(
        const int* __restrict__ ei, const float* __restrict__ partial,
        const float* __restrict__ fc_wT,  const float* __restrict__ fc_b,
        const float* __restrict__ xyz_w,  const float* __restrict__ xyz_b,
        const float* __restrict__ wpqr_w, const float* __restrict__ wpqr_b,
        float* __restrict__ out) {
    int e = blockIdx.x;
    int t = threadIdx.x;                 // = feature index f
    int a0 = ei[e], a1 = ei[N_EDGES + e];
    int pi = min(a0, a1), pj = max(a0, a1);
    int rank = pi * 8 - ((pi * (pi + 1)) >> 1) + pj;
    __shared__ float pl[CO];
    if (t < CO) {
        float s = 0.f;
#pragma unroll
        for (int rt = 0; rt < 16; ++rt)
            s += partial[(rt * 36 + rank) * 64 + t];
        pl[t] = s * (1.f / 4096.f);
    }
    __syncthreads();

    float d = fc_b[t];
#pragma unroll
    for (int c = 0; c < CO; ++c)
        d = fmaf(pl[c], fc_wT[c * FEAT + t], d);
    d = fmaxf(d, 0.f);

    float s[6];
#pragma unroll
    for (int r = 0; r < 3; ++r) {
        s[r]     = d * xyz_w[r * FEAT + t];
        s[3 + r] = d * wpqr_w[r * FEAT + t];
    }
#pragma unroll
    for (int r = 0; r < 6; ++r)
#pragma unroll
        for (int off = 32; off > 0; off >>= 1)
            s[r] += __shfl_down(s[r], off, 64);

    __shared__ float red[16][6];
    if ((t & 63) == 0) {
#pragma unroll
        for (int r = 0; r < 6; ++r) red[t >> 6][r] = s[r];
    }
    __syncthreads();
    if (t < 6) {
        float v = 0.f;
#pragma unroll
        for (int w = 0; w < 16; ++w) v += red[w][t];
        v += (t < 3) ? xyz_b[t] : wpqr_b[t - 3];
        out[48 + e * 6 + t] = v;
        if (e < 8) out[e * 6 + t] = v;
    }
}

// ---------------------------------------------------------------------------
extern "C" void kernel_launch(void* const* d_in, const int* in_sizes, int n_in,
                              void* d_out, int out_size, void* d_ws, size_t ws_size,
                              hipStream_t stream) {
    const float* x        = (const float*)d_in[0];
    const int*   ei       = (const int*)d_in[1];
    const float* conv1_w  = (const float*)d_in[2];
    const float* bn_gamma = (const float*)d_in[3];
    const float* bn_beta  = (const float*)d_in[4];
    const float* bn_mean  = (const float*)d_in[5];
    const float* bn_var   = (const float*)d_in[6];
    const float* fc_w     = (const float*)d_in[7];
    const float* fc_b     = (const float*)d_in[8];
    const float* xyz_w    = (const float*)d_in[9];
    const float* xyz_b    = (const float*)d_in[10];
    const float* wpqr_w   = (const float*)d_in[11];
    const float* wpqr_b   = (const float*)d_in[12];
    float* out = (float*)d_out;

    char* ws = (char*)d_ws;
    float*          partial = (float*)(ws + OFF_PARTIAL);
    unsigned*       xpad    = (unsigned*)(ws + OFF_XPAD);
    unsigned short* wb2     = (unsigned short*)(ws + OFF_WB);
    unsigned short* A2      = (unsigned short*)(ws + OFF_A);
    unsigned short* B2      = (unsigned short*)(ws + OFF_B);
    float*          fc_wT   = (float*)(ws + OFF_FCWT);

    int img_work = 8 * 3 * 262 * XROW;
    prep_kernel<<<(img_work + 255) / 256, 256, 0, stream>>>(
        x, conv1_w, bn_gamma, bn_var, fc_w, xpad, wb2, fc_wT);
    conv_kernel<<<1024, 256, 0, stream>>>(xpad, wb2, bn_gamma, bn_beta,
                                          bn_mean, bn_var, A2, B2);
    pool_kernel<<<1024, 320, 0, stream>>>(A2, B2, partial);
    head_kernel<<<64, 1024, 0, stream>>>(ei, partial, fc_wT, fc_b,
                                         xyz_w, xyz_b, wpqr_w, wpqr_b, out);
}

// Round 4
// 119.092 us; speedup vs baseline: 1.0942x; 1.0186x over previous
//
#include <hip/hip_runtime.h>
#include <hip/hip_bf16.h>

// Problem constants
#define N_NODES 8
#define N_EDGES 64
#define CO 64
#define OH 128
#define OW 128
#define FEAT 1024
#define BN_EPS 1e-5f

// Workspace layout (bytes):
//   partial @ 0        : 16 rt x 36 pairs x 64 c fp32 = 147,456 (pad 151,552)
//   (xpad region unused — conv stages directly from x, parity-aligned)
//   wb2     @ 3471616  : 24*128*8 bf16 = 49,152
//   A2      @ 3520768  : 16,777,216
//   B2      @ 20297984 : 16,777,216
//   fc_wT   @ 37075200 : 64*1024 f32 = 262,144
#define OFF_PARTIAL 0
#define OFF_WB      3471616
#define OFF_A       3520768
#define OFF_B       20297984
#define OFF_FCWT    37075200

#define RS_W 136        // conv raw row stride in u32 words

typedef short bf16x8 __attribute__((ext_vector_type(8)));
typedef float f32x4  __attribute__((ext_vector_type(4)));

__device__ __forceinline__ unsigned short f2bf(float f) {   // RNE f32->bf16
    unsigned u = __float_as_uint(f);
    u += 0x7fffu + ((u >> 16) & 1u);
    return (unsigned short)(u >> 16);
}
__device__ __forceinline__ float blo(unsigned u) { return __uint_as_float(u << 16); }
__device__ __forceinline__ float bhi(unsigned u) { return __uint_as_float(u & 0xffff0000u); }

// ---------------------------------------------------------------------------
// K0: micro-prep — wb2 weight repack (PARITY-SHIFTED: slot kx holds tap kx-1,
// slot 0 zero) + fc_w transpose. Image conversion fused into conv staging.
__global__ __launch_bounds__(256) void prep_kernel(
        const float* __restrict__ w,
        const float* __restrict__ gamma, const float* __restrict__ var,
        const float* __restrict__ fc_w,
        unsigned short* __restrict__ wb2, float* __restrict__ fc_wT) {
    int idx = blockIdx.x * 256 + threadIdx.x;
    if (idx < 2 * 64 * 192) {
        int tp = idx % 192;
        int c  = (idx / 192) & 63;
        int h  = idx / (192 * 64);
        int rr = tp >> 3, kx = tp & 7;
        float val = 0.f;
        if (rr < 21 && kx >= 1) {       // slot kx = tap kx-1 (parity shift)
            int ci = rr / 7, ky = rr % 7;
            float sc = gamma[c] * rsqrtf(var[c] + BN_EPS);
            val = w[((c * 6 + h * 3 + ci) * 7 + ky) * 7 + (kx - 1)] * sc;
        }
        wb2[(rr * 128 + h * 64 + c) * 8 + kx] = f2bf(val);
    }
    if (idx < CO * FEAT) {                 // fc_wT[c][f] = fc_w[f][c]
        int c = idx >> 10, f = idx & 1023;
        fc_wT[idx] = fc_w[f * CO + c];
    }
}

// ---------------------------------------------------------------------------
// K1: MFMA conv, staging fused from x (fp32) directly.
// rawu layout PARITY-SHIFTED: word u of a row covers cols (2u-4, 2u-3), so a
// float4 load of cols 4q..4q+3 packs to ONE aligned uint2 LDS write (R2's
// fusion failed on the old parity: misaligned scalar clamp loads, -11us).
// afrag slot j = col 2ox-4+j; wb2 slot j = tap j-1 -> identical dot product.
// Wave = (hg = A/B half, wg = px half): 64px x 64chp tile, acc[4][4].
__global__ __launch_bounds__(256, 3) void conv_kernel(
        const float* __restrict__ x, const unsigned short* __restrict__ wb2,
        const float* __restrict__ gamma, const float* __restrict__ beta,
        const float* __restrict__ mean,  const float* __restrict__ var,
        unsigned short* __restrict__ A2, unsigned short* __restrict__ B2) {
    int bx  = blockIdx.x;
    int r16 = bx & 7;                  // XCD-pinned row-group (matches pool)
    int idx = bx >> 3;
    int n   = idx >> 4;
    int oy  = (r16 << 4) + (idx & 15);
    int t   = threadIdx.x;

    // one 32 KB buffer: rawu [24][136] u32 (13 KB), reused as T [128][128] bf16
    __shared__ __align__(16) char smem[32768];
    unsigned* rawu = (unsigned*)smem;

    // border zeros: words {0,1,130..135} of rows 0..20; rows 21..23 fully
    if (t < 168) {
        int rr = t >> 3, wsel = t & 7;
        int u = (wsel < 2) ? wsel : (128 + wsel);
        rawu[rr * RS_W + u] = 0u;
    } else if (t < 270) {
        int k2 = t - 168;
        int rr = 21 + k2 / 34, g = k2 % 34;
        *(uint4*)&rawu[rr * RS_W + 4 * g] = make_uint4(0u, 0u, 0u, 0u);
    }

    // main stage: 21 (ci,ky) rows x 64 float4 granules, fully coalesced.
    // cols 4q..4q+3 -> words 2q+2, 2q+3 (parity-aligned 8B write).
    const float* xn = x + (size_t)n * (3 * 65536);
    for (int k = t; k < 1344; k += 256) {
        int rr = k >> 6, q = k & 63;
        int ci = (rr * 147) >> 10;      // rr/7 for rr<24
        int ky = rr - ci * 7;
        int iy = 2 * oy + ky - 3;
        uint2 pk = make_uint2(0u, 0u);
        if ((unsigned)iy < 256u) {
            float4 f = *(const float4*)(xn + ci * 65536 + iy * 256 + 4 * q);
            pk.x = (unsigned)f2bf(f.x) | ((unsigned)f2bf(f.y) << 16);
            pk.y = (unsigned)f2bf(f.z) | ((unsigned)f2bf(f.w) << 16);
        }
        *(uint2*)&rawu[rr * RS_W + 2 * q + 2] = pk;
    }
    __syncthreads();

    int wv = t >> 6, lane = t & 63;
    int hg = wv >> 1;                   // A/B half (chp 0-63 vs 64-127)
    int wg = wv & 1;                    // px half (64 px)
    int quad = lane >> 4, m = lane & 15;

    f32x4 acc[4][4];
#pragma unroll
    for (int ct = 0; ct < 4; ++ct)
#pragma unroll
        for (int nt = 0; nt < 4; ++nt)
            acc[ct][nt] = (f32x4){0.f, 0.f, 0.f, 0.f};

    const bf16x8* wbv = (const bf16x8*)wb2;

#pragma unroll 2
    for (int s = 0; s < 6; ++s) {
        int rq = 4 * s + quad;
        bf16x8 afrag[4];                // image: A[m=px][k]
#pragma unroll
        for (int nt = 0; nt < 4; ++nt) {
            int ox = 64 * wg + 16 * nt + m;
            int base = rq * RS_W + ox;
            union { unsigned u[4]; bf16x8 v; } bb;
            bb.u[0] = rawu[base];     bb.u[1] = rawu[base + 1];
            bb.u[2] = rawu[base + 2]; bb.u[3] = rawu[base + 3];
            afrag[nt] = bb.v;
        }
#pragma unroll
        for (int ct = 0; ct < 4; ++ct) {
            bf16x8 wfrag = wbv[rq * 128 + hg * 64 + 16 * ct + m];  // L1-hot
#pragma unroll
            for (int nt = 0; nt < 4; ++nt)
                acc[ct][nt] = __builtin_amdgcn_mfma_f32_16x16x32_bf16(
                                  afrag[nt], wfrag, acc[ct][nt], 0, 0, 0);
        }
    }

    float sh[4] = {0.f, 0.f, 0.f, 0.f};
    if (hg) {                           // BN shift folded into B-half only
#pragma unroll
        for (int ct = 0; ct < 4; ++ct) {
            int c = 16 * ct + m;
            float sc = gamma[c] * rsqrtf(var[c] + BN_EPS);
            sh[ct] = beta[c] - mean[c] * sc;
        }
    }

    __syncthreads();                    // smem reuse: T transpose buffer
    unsigned short* T = (unsigned short*)smem;   // [128 chp][128 px], swizzled

#pragma unroll
    for (int ct = 0; ct < 4; ++ct) {
        int chp = hg * 64 + 16 * ct + m;
        int sw  = (chp & 7) << 2;       // XOR swizzle key (granule = 4 shorts)
#pragma unroll
        for (int nt = 0; nt < 4; ++nt) {
            int px0 = 64 * wg + 16 * nt + 4 * quad;
            float v0 = acc[ct][nt][0] + sh[ct];
            float v1 = acc[ct][nt][1] + sh[ct];
            float v2 = acc[ct][nt][2] + sh[ct];
            float v3 = acc[ct][nt][3] + sh[ct];
            uint2 pk;
            pk.x = (unsigned)f2bf(v0) | ((unsigned)f2bf(v1) << 16);
            pk.y = (unsigned)f2bf(v2) | ((unsigned)f2bf(v3) << 16);
            int gs = ((px0 >> 2) ^ sw);
            *(uint2*)&T[chp * 128 + gs * 4] = pk;
        }
    }
    __syncthreads();

    // coalesced store: 4 passes of (32 ch-rows x 8 16-px slots), 2x uint4 each
#pragma unroll
    for (int rr = 0; rr < 4; ++rr) {
        int row = rr * 32 + (t >> 3), slot = t & 7;
        int hh = row >> 6, ch = row & 63;
        int swr = (row & 7) << 2;
        unsigned short* dst = (hh ? B2 : A2)
                            + ((size_t)(n * CO + ch) << 14) + (oy << 7) + slot * 16;
#pragma unroll
        for (int i = 0; i < 2; ++i) {
            int g  = slot * 4 + i * 2;  // granule of px slot*16 + i*8
            int gs = g ^ swr;
            *(uint4*)(dst + i * 8) = *(uint4*)&T[row * 128 + gs * 4];
        }
    }
}

// ---------------------------------------------------------------------------
// K2: pool over 36 distinct pairs -> non-atomic partial[rt][pair][c]
// (exact R1 configuration — the measured best).
__global__ __launch_bounds__(256, 4) void pool_kernel(
        const unsigned short* __restrict__ A2,
        const unsigned short* __restrict__ B2,
        float* __restrict__ partial) {
    int pb  = blockIdx.x;
    int xcd = pb & 7;
    int q   = pb >> 3;
    int c   = q >> 1;
    int rt  = xcd * 2 + (q & 1);
    int t   = threadIdx.x;

    __shared__ unsigned short S[2 * 8 * 9 * 128];   // plane 1152, row 128

    for (int k = t; k < 2304; k += 256) {
        int slot = k & 15;
        int r    = (k >> 4) % 9;
        int tn   = (k >> 4) / 9;
        int grow = 8 * rt - 1 + r;
        uint4 v = make_uint4(0u, 0u, 0u, 0u);
        if (grow >= 0) {
            const unsigned short* src = (tn >= 8) ? B2 : A2;
            int node = tn & 7;
            v = *(const uint4*)(src + ((size_t)(node * CO + c) << 14)
                                    + (grow << 7) + slot * 8);
        }
        *(uint4*)&S[tn * 1152 + (r << 7) + slot * 8] = v;
    }
    __syncthreads();

    int wv = t >> 6, lane = t & 63;
    int esub = lane >> 4, tc = lane & 15;

    for (int i = 0; i < 3; ++i) {
        int sidx = 12 * wv + 4 * i + esub;          // pair slot 0..47
        bool valid = sidx < 36;
        int ss = valid ? sidx : 0;
        int pi = 0, rem = ss;                        // unrank (pi<=pj)
        while (rem >= 8 - pi) { rem -= 8 - pi; ++pi; }
        int pj = pi + rem;
        const unsigned short* pa  = &S[pi * 1152];
        const unsigned short* pb2 = &S[(8 + pj) * 1152];

        float mx[4][4];
#pragma unroll
        for (int p = 0; p < 4; ++p)
#pragma unroll
            for (int qq = 0; qq < 4; ++qq) mx[p][qq] = 0.f;

#pragma unroll
        for (int r = 0; r < 9; ++r) {
            uint4 ga = *(const uint4*)(pa + (r << 7) + tc * 8);
            uint4 gb = *(const uint4*)(pb2 + (r << 7) + tc * 8);
            float ha = 0.f, hb = 0.f;
            if (tc > 0) {
                ha = bhi(*(const unsigned*)(pa + (r << 7) + tc * 8 - 2));
                hb = bhi(*(const unsigned*)(pb2 + (r << 7) + tc * 8 - 2));
            }
            float z0 = ha + hb;
            float z1 = blo(ga.x) + blo(gb.x), z2 = bhi(ga.x) + bhi(gb.x);
            float z3 = blo(ga.y) + blo(gb.y), z4 = bhi(ga.y) + bhi(gb.y);
            float z5 = blo(ga.z) + blo(gb.z), z6 = bhi(ga.z) + bhi(gb.z);
            float z7 = blo(ga.w) + blo(gb.w), z8 = bhi(ga.w) + bhi(gb.w);
            float h0 = fmaxf(fmaxf(z0, z1), z2);
            float h1 = fmaxf(fmaxf(z2, z3), z4);
            float h2 = fmaxf(fmaxf(z4, z5), z6);
            float h3 = fmaxf(fmaxf(z6, z7), z8);
            if (r & 1) {
                int p = (r - 1) >> 1;
                mx[p][0] = fmaxf(mx[p][0], h0); mx[p][1] = fmaxf(mx[p][1], h1);
                mx[p][2] = fmaxf(mx[p][2], h2); mx[p][3] = fmaxf(mx[p][3], h3);
            } else {
                if (r >= 2) {
                    int p = (r >> 1) - 1;
                    mx[p][0] = fmaxf(mx[p][0], h0); mx[p][1] = fmaxf(mx[p][1], h1);
                    mx[p][2] = fmaxf(mx[p][2], h2); mx[p][3] = fmaxf(mx[p][3], h3);
                }
                if (r <= 6) {
                    int p = r >> 1;
                    mx[p][0] = fmaxf(mx[p][0], h0); mx[p][1] = fmaxf(mx[p][1], h1);
                    mx[p][2] = fmaxf(mx[p][2], h2); mx[p][3] = fmaxf(mx[p][3], h3);
                }
            }
        }

        float sum = 0.f;
#pragma unroll
        for (int p = 0; p < 4; ++p)
#pragma unroll
            for (int qq = 0; qq < 4; ++qq) sum += fmaxf(mx[p][qq], 0.f);

        sum += __shfl_down(sum, 8, 64);
        sum += __shfl_down(sum, 4, 64);
        sum += __shfl_down(sum, 2, 64);
        sum += __shfl_down(sum, 1, 64);
        if (tc == 0 && valid)
            partial[(rt * 36 + sidx) * 64 + c] = sum;
    }
}

// ---------------------------------------------------------------------------
// K3: head — 64 blocks x 1024 thr, thread t = feature f; fc_wT coalesced.
__global__ __launch_bounds__(1024) void head_kernel(
        const int* __restrict__ ei, const float* __restrict__ partial,
        const float* __restrict__ fc_wT,  const float* __restrict__ fc_b,
        const float* __restrict__ xyz_w,  const float* __restrict__ xyz_b,
        const float* __restrict__ wpqr_w, const float* __restrict__ wpqr_b,
        float* __restrict__ out) {
    int e = blockIdx.x;
    int t = threadIdx.x;                 // = feature index f
    int a0 = ei[e], a1 = ei[N_EDGES + e];
    int pi = min(a0, a1), pj = max(a0, a1);
    int rank = pi * 8 - ((pi * (pi + 1)) >> 1) + pj;
    __shared__ float pl[CO];
    if (t < CO) {
        float s = 0.f;
#pragma unroll
        for (int rt = 0; rt < 16; ++rt)
            s += partial[(rt * 36 + rank) * 64 + t];
        pl[t] = s * (1.f / 4096.f);
    }
    __syncthreads();

    float d = fc_b[t];
#pragma unroll
    for (int c = 0; c < CO; ++c)
        d = fmaf(pl[c], fc_wT[c * FEAT + t], d);
    d = fmaxf(d, 0.f);

    float s[6];
#pragma unroll
    for (int r = 0; r < 3; ++r) {
        s[r]     = d * xyz_w[r * FEAT + t];
        s[3 + r] = d * wpqr_w[r * FEAT + t];
    }
#pragma unroll
    for (int r = 0; r < 6; ++r)
#pragma unroll
        for (int off = 32; off > 0; off >>= 1)
            s[r] += __shfl_down(s[r], off, 64);

    __shared__ float red[16][6];
    if ((t & 63) == 0) {
#pragma unroll
        for (int r = 0; r < 6; ++r) red[t >> 6][r] = s[r];
    }
    __syncthreads();
    if (t < 6) {
        float v = 0.f;
#pragma unroll
        for (int w = 0; w < 16; ++w) v += red[w][t];
        v += (t < 3) ? xyz_b[t] : wpqr_b[t - 3];
        out[48 + e * 6 + t] = v;
        if (e < 8) out[e * 6 + t] = v;
    }
}

// ---------------------------------------------------------------------------
extern "C" void kernel_launch(void* const* d_in, const int* in_sizes, int n_in,
                              void* d_out, int out_size, void* d_ws, size_t ws_size,
                              hipStream_t stream) {
    const float* x        = (const float*)d_in[0];
    const int*   ei       = (const int*)d_in[1];
    const float* conv1_w  = (const float*)d_in[2];
    const float* bn_gamma = (const float*)d_in[3];
    const float* bn_beta  = (const float*)d_in[4];
    const float* bn_mean  = (const float*)d_in[5];
    const float* bn_var   = (const float*)d_in[6];
    const float* fc_w     = (const float*)d_in[7];
    const float* fc_b     = (const float*)d_in[8];
    const float* xyz_w    = (const float*)d_in[9];
    const float* xyz_b    = (const float*)d_in[10];
    const float* wpqr_w   = (const float*)d_in[11];
    const float* wpqr_b   = (const float*)d_in[12];
    float* out = (float*)d_out;

    char* ws = (char*)d_ws;
    float*          partial = (float*)(ws + OFF_PARTIAL);
    unsigned short* wb2     = (unsigned short*)(ws + OFF_WB);
    unsigned short* A2      = (unsigned short*)(ws + OFF_A);
    unsigned short* B2      = (unsigned short*)(ws + OFF_B);
    float*          fc_wT   = (float*)(ws + OFF_FCWT);

    prep_kernel<<<256, 256, 0, stream>>>(conv1_w, bn_gamma, bn_var,
                                         fc_w, wb2, fc_wT);
    conv_kernel<<<1024, 256, 0, stream>>>(x, wb2, bn_gamma, bn_beta,
                                          bn_mean, bn_var, A2, B2);
    pool_kernel<<<1024, 256, 0, stream>>>(A2, B2, partial);
    head_kernel<<<64, 1024, 0, stream>>>(ei, partial, fc_wT, fc_b,
                                         xyz_w, xyz_b, wpqr_w, wpqr_b, out);
}